// Round 2
// baseline (1208.648 us; speedup 1.0000x reference)
//
#include <hip/hip_runtime.h>
#include <math.h>

#define TOKS 8192
#define HD 1024
#define ID 2048
#define NE 8

typedef __bf16 bf16_t;
typedef __bf16 bf16x8 __attribute__((ext_vector_type(8)));
typedef __bf16 bf16x4 __attribute__((ext_vector_type(4)));
typedef float f32x4 __attribute__((ext_vector_type(4)));

// ---------------- workspace layout (bytes) ----------------
#define WS_COUNTS 0
#define WS_OFFSETS 32
#define WS_CURSOR 64
#define WS_BTOK 128
#define WS_BW (128 + 65536)
#define WS_TE (128 + 2 * 65536)
#define WS_TW (128 + 3 * 65536)
#define WS_XB 262400ull
#define WS_H1 (262400ull + 16777216ull)
// total ≈ 84.2 MB

// ---------------- zero out + counts (replaces hipMemsetAsync: NOT graph-capturable) ----
__global__ void zero_kernel(float* __restrict__ out, int* __restrict__ counts) {
  const int i = (blockIdx.x * 256 + threadIdx.x) * 4;
  *(float4*)(out + i) = make_float4(0.f, 0.f, 0.f, 0.f);
  if (blockIdx.x == 0 && threadIdx.x < NE) counts[threadIdx.x] = 0;
}

// ---------------- gating: 1 wave per token ----------------
__global__ void gate_kernel(const float* __restrict__ x, const float* __restrict__ Wg,
                            int* __restrict__ tok_e, float* __restrict__ tok_w,
                            int* __restrict__ counts) {
  const int t = blockIdx.x;
  const int lane = threadIdx.x;
  float acc[NE];
#pragma unroll
  for (int e = 0; e < NE; ++e) acc[e] = 0.f;
  const float* xrow = x + (size_t)t * HD;
#pragma unroll
  for (int i = 0; i < HD / 64; ++i) {
    const int h = i * 64 + lane;
    const float xv = xrow[h];
    const float* wr = Wg + h * NE;
#pragma unroll
    for (int e = 0; e < NE; ++e) acc[e] += xv * wr[e];
  }
#pragma unroll
  for (int off = 32; off >= 1; off >>= 1) {
#pragma unroll
    for (int e = 0; e < NE; ++e) acc[e] += __shfl_xor(acc[e], off);
  }
  if (lane == 0) {
    int i1 = 0;
    float l1 = acc[0];
#pragma unroll
    for (int e = 1; e < NE; ++e) {
      if (acc[e] > l1) { l1 = acc[e]; i1 = e; }
    }
    int i2 = -1;
    float l2 = -3.4e38f;
#pragma unroll
    for (int e = 0; e < NE; ++e) {
      if (e != i1 && acc[e] > l2) { l2 = acc[e]; i2 = e; }
    }
    const float q = expf(l2 - l1);       // <= 1
    const float w1 = 1.f / (1.f + q);    // renormalized top-2 weights
    tok_e[2 * t] = i1;
    tok_e[2 * t + 1] = i2;
    tok_w[2 * t] = w1;
    tok_w[2 * t + 1] = q * w1;
    atomicAdd(&counts[i1], 1);
    atomicAdd(&counts[i2], 1);
  }
}

__global__ void scan_kernel(const int* __restrict__ counts, int* __restrict__ offsets,
                            int* __restrict__ cursor) {
  if (threadIdx.x == 0) {
    int s = 0;
    for (int e = 0; e < NE; ++e) {
      offsets[e] = s;
      cursor[e] = s;
      s += counts[e];
    }
  }
}

__global__ void scatter_kernel(const int* __restrict__ tok_e, const float* __restrict__ tok_w,
                               int* __restrict__ cursor, int* __restrict__ bucket_tok,
                               float* __restrict__ bucket_w) {
  const int idx = blockIdx.x * 256 + threadIdx.x;  // 0..16383
  const int e = tok_e[idx];
  const int pos = atomicAdd(&cursor[e], 1) & (2 * TOKS - 1);  // mask: defense vs OOB
  bucket_tok[pos] = idx >> 1;
  bucket_w[pos] = tok_w[idx];
}

__global__ void convert_x_kernel(const float* __restrict__ x, bf16_t* __restrict__ xb) {
  const int i = (blockIdx.x * 256 + threadIdx.x) * 4;
  const float4 v = *(const float4*)(x + i);
  bf16x4 o;
  o[0] = (bf16_t)v.x;
  o[1] = (bf16_t)v.y;
  o[2] = (bf16_t)v.z;
  o[3] = (bf16_t)v.w;
  *(bf16x4*)(xb + i) = o;
}

// ---------------- expert GEMMs ----------------
#define BM 128
#define BN 64
#define BK 32
#define LDA 40
#define LDB 40

__global__ __launch_bounds__(256) void gemm1_kernel(
    const bf16_t* __restrict__ xb, const float* __restrict__ W1, const float* __restrict__ b1,
    const int* __restrict__ counts, const int* __restrict__ offsets,
    const int* __restrict__ bucket_tok, bf16_t* __restrict__ h1) {
  const int e = blockIdx.z;
  const int n_e = counts[e];
  const int m_base = blockIdx.x * BM;
  if (m_base >= n_e) return;
  const int n_base = blockIdx.y * BN;
  const int off = offsets[e];

  __shared__ bf16_t As[BM * LDA];
  __shared__ bf16_t Bs[BN * LDB];

  const int tid = threadIdx.x;
  const int wave = tid >> 6;
  const int lane = tid & 63;
  const int quad = lane >> 4;
  const int lrow = lane & 15;

  // A staging: each thread loads 16 bf16 of one gathered x row
  const int a_row = tid >> 1;
  const int a_c0 = (tid & 1) * 16;
  int rr = m_base + a_row;
  if (rr >= n_e) rr = m_base;
  const int tok = bucket_tok[off + rr];
  const bf16_t* a_gptr = xb + (size_t)tok * HD + a_c0;

  // B staging: thread reads 8 consecutive f32 along n from W1[k][n], writes transposed [n][k]
  const int b_kk = tid >> 3;
  const int b_nn0 = (tid & 7) * 8;
  const float* b_gbase = W1 + ((size_t)e * HD + b_kk) * ID + n_base + b_nn0;

  f32x4 acc[2][4];
#pragma unroll
  for (int mt = 0; mt < 2; ++mt)
#pragma unroll
    for (int nt = 0; nt < 4; ++nt)
#pragma unroll
      for (int r = 0; r < 4; ++r) acc[mt][nt][r] = 0.f;

  for (int k0 = 0; k0 < HD; k0 += BK) {
    __syncthreads();
    const bf16x8 av0 = *(const bf16x8*)(a_gptr + k0);
    const bf16x8 av1 = *(const bf16x8*)(a_gptr + k0 + 8);
    const float4 bv0 = *(const float4*)(b_gbase + (size_t)k0 * ID);
    const float4 bv1 = *(const float4*)(b_gbase + (size_t)k0 * ID + 4);
    *(bf16x8*)(As + a_row * LDA + a_c0) = av0;
    *(bf16x8*)(As + a_row * LDA + a_c0 + 8) = av1;
    bf16_t bc[8];
    bc[0] = (bf16_t)bv0.x; bc[1] = (bf16_t)bv0.y; bc[2] = (bf16_t)bv0.z; bc[3] = (bf16_t)bv0.w;
    bc[4] = (bf16_t)bv1.x; bc[5] = (bf16_t)bv1.y; bc[6] = (bf16_t)bv1.z; bc[7] = (bf16_t)bv1.w;
#pragma unroll
    for (int j = 0; j < 8; ++j) Bs[(b_nn0 + j) * LDB + b_kk] = bc[j];
    __syncthreads();

    bf16x8 af[2], bfr[4];
    af[0] = *(const bf16x8*)(As + (wave * 32 + lrow) * LDA + quad * 8);
    af[1] = *(const bf16x8*)(As + (wave * 32 + 16 + lrow) * LDA + quad * 8);
#pragma unroll
    for (int nt = 0; nt < 4; ++nt)
      bfr[nt] = *(const bf16x8*)(Bs + (nt * 16 + lrow) * LDB + quad * 8);
#pragma unroll
    for (int mt = 0; mt < 2; ++mt)
#pragma unroll
      for (int nt = 0; nt < 4; ++nt)
        acc[mt][nt] =
            __builtin_amdgcn_mfma_f32_16x16x32_bf16(af[mt], bfr[nt], acc[mt][nt], 0, 0, 0);
  }

#pragma unroll
  for (int mt = 0; mt < 2; ++mt) {
#pragma unroll
    for (int r = 0; r < 4; ++r) {
      const int gm = m_base + wave * 32 + mt * 16 + quad * 4 + r;
      if (gm < n_e) {
#pragma unroll
        for (int nt = 0; nt < 4; ++nt) {
          const int gi = n_base + nt * 16 + lrow;
          float v = acc[mt][nt][r] + b1[e * ID + gi];
          v = 0.5f * v * (1.f + erff(v * 0.70710678118654752f));  // exact-erf GELU
          h1[(size_t)(off + gm) * ID + gi] = (bf16_t)v;
        }
      }
    }
  }
}

__global__ __launch_bounds__(256) void gemm2_kernel(
    const bf16_t* __restrict__ h1, const float* __restrict__ W2, const float* __restrict__ b2,
    const int* __restrict__ counts, const int* __restrict__ offsets,
    const int* __restrict__ bucket_tok, const float* __restrict__ bucket_w,
    float* __restrict__ out) {
  const int e = blockIdx.z;
  const int n_e = counts[e];
  const int m_base = blockIdx.x * BM;
  if (m_base >= n_e) return;
  const int n_base = blockIdx.y * BN;
  const int off = offsets[e];

  __shared__ bf16_t As[BM * LDA];
  __shared__ bf16_t Bs[BN * LDB];

  const int tid = threadIdx.x;
  const int wave = tid >> 6;
  const int lane = tid & 63;
  const int quad = lane >> 4;
  const int lrow = lane & 15;

  const int a_row = tid >> 1;
  const int a_c0 = (tid & 1) * 16;
  int rr = m_base + a_row;
  if (rr >= n_e) rr = m_base;
  const bf16_t* a_gptr = h1 + (size_t)(off + rr) * ID + a_c0;

  const int b_kk = tid >> 3;
  const int b_nn0 = (tid & 7) * 8;
  const float* b_gbase = W2 + ((size_t)e * ID + b_kk) * HD + n_base + b_nn0;

  f32x4 acc[2][4];
#pragma unroll
  for (int mt = 0; mt < 2; ++mt)
#pragma unroll
    for (int nt = 0; nt < 4; ++nt)
#pragma unroll
      for (int r = 0; r < 4; ++r) acc[mt][nt][r] = 0.f;

  for (int k0 = 0; k0 < ID; k0 += BK) {
    __syncthreads();
    const bf16x8 av0 = *(const bf16x8*)(a_gptr + k0);
    const bf16x8 av1 = *(const bf16x8*)(a_gptr + k0 + 8);
    const float4 bv0 = *(const float4*)(b_gbase + (size_t)k0 * HD);
    const float4 bv1 = *(const float4*)(b_gbase + (size_t)k0 * HD + 4);
    *(bf16x8*)(As + a_row * LDA + a_c0) = av0;
    *(bf16x8*)(As + a_row * LDA + a_c0 + 8) = av1;
    bf16_t bc[8];
    bc[0] = (bf16_t)bv0.x; bc[1] = (bf16_t)bv0.y; bc[2] = (bf16_t)bv0.z; bc[3] = (bf16_t)bv0.w;
    bc[4] = (bf16_t)bv1.x; bc[5] = (bf16_t)bv1.y; bc[6] = (bf16_t)bv1.z; bc[7] = (bf16_t)bv1.w;
#pragma unroll
    for (int j = 0; j < 8; ++j) Bs[(b_nn0 + j) * LDB + b_kk] = bc[j];
    __syncthreads();

    bf16x8 af[2], bfr[4];
    af[0] = *(const bf16x8*)(As + (wave * 32 + lrow) * LDA + quad * 8);
    af[1] = *(const bf16x8*)(As + (wave * 32 + 16 + lrow) * LDA + quad * 8);
#pragma unroll
    for (int nt = 0; nt < 4; ++nt)
      bfr[nt] = *(const bf16x8*)(Bs + (nt * 16 + lrow) * LDB + quad * 8);
#pragma unroll
    for (int mt = 0; mt < 2; ++mt)
#pragma unroll
      for (int nt = 0; nt < 4; ++nt)
        acc[mt][nt] =
            __builtin_amdgcn_mfma_f32_16x16x32_bf16(af[mt], bfr[nt], acc[mt][nt], 0, 0, 0);
  }

#pragma unroll
  for (int mt = 0; mt < 2; ++mt) {
#pragma unroll
    for (int r = 0; r < 4; ++r) {
      const int gm = m_base + wave * 32 + mt * 16 + quad * 4 + r;
      if (gm < n_e) {
        const int pos = off + gm;
        const int tokid = bucket_tok[pos];
        const float w = bucket_w[pos];
        float* orow = out + (size_t)tokid * HD;
#pragma unroll
        for (int nt = 0; nt < 4; ++nt) {
          const int gh = n_base + nt * 16 + lrow;
          const float v = acc[mt][nt][r] + b2[e * HD + gh];
          atomicAdd(orow + gh, w * v);
        }
      }
    }
  }
}

extern "C" void kernel_launch(void* const* d_in, const int* in_sizes, int n_in,
                              void* d_out, int out_size, void* d_ws, size_t ws_size,
                              hipStream_t stream) {
  const float* x = (const float*)d_in[0];
  const float* Wg = (const float*)d_in[1];
  const float* W1 = (const float*)d_in[2];
  const float* b1 = (const float*)d_in[3];
  const float* W2 = (const float*)d_in[4];
  const float* b2 = (const float*)d_in[5];
  float* out = (float*)d_out;
  char* ws = (char*)d_ws;

  int* counts = (int*)(ws + WS_COUNTS);
  int* offsets = (int*)(ws + WS_OFFSETS);
  int* cursor = (int*)(ws + WS_CURSOR);
  int* bucket_tok = (int*)(ws + WS_BTOK);
  float* bucket_w = (float*)(ws + WS_BW);
  int* tok_e = (int*)(ws + WS_TE);
  float* tok_w = (float*)(ws + WS_TW);
  bf16_t* xb = (bf16_t*)(ws + WS_XB);
  bf16_t* h1 = (bf16_t*)(ws + WS_H1);

  // zero d_out and counts via a kernel — hipMemsetAsync is NOT graph-capturable
  zero_kernel<<<(TOKS * HD / 4) / 256, 256, 0, stream>>>(out, counts);
  gate_kernel<<<TOKS, 64, 0, stream>>>(x, Wg, tok_e, tok_w, counts);
  scan_kernel<<<1, 64, 0, stream>>>(counts, offsets, cursor);
  scatter_kernel<<<TOKS * 2 / 256, 256, 0, stream>>>(tok_e, tok_w, cursor, bucket_tok, bucket_w);
  convert_x_kernel<<<TOKS * HD / 4 / 256, 256, 0, stream>>>(x, xb);
  gemm1_kernel<<<dim3(TOKS / BM, ID / BN, NE), 256, 0, stream>>>(xb, W1, b1, counts, offsets,
                                                                 bucket_tok, h1);
  gemm2_kernel<<<dim3(TOKS / BM, HD / BN, NE), 256, 0, stream>>>(h1, W2, b2, counts, offsets,
                                                                 bucket_tok, bucket_w, out);
}

// Round 3
// 917.899 us; speedup vs baseline: 1.3168x; 1.3168x over previous
//
#include <hip/hip_runtime.h>
#include <math.h>

#define TOKS 8192
#define HD 1024
#define ID 2048
#define NE 8

typedef __bf16 bf16_t;
typedef __bf16 bf16x8 __attribute__((ext_vector_type(8)));
typedef float f32x4 __attribute__((ext_vector_type(4)));

// async global->LDS, 16 bytes per lane. LDS dest: wave-uniform base + lane*16.
#define GLOAD(gp, lp)                                                \
  __builtin_amdgcn_global_load_lds(                                  \
      (const __attribute__((address_space(1))) void*)(gp),           \
      (__attribute__((address_space(3))) void*)(lp), 16, 0, 0)

// ---------------- workspace layout (bytes) ----------------
#define WS_COUNTS 0
#define WS_OFFSETS 32
#define WS_CURSOR 64
#define WS_BTOK 128
#define WS_BW (128 + 65536)
#define WS_TE (128 + 2 * 65536)
#define WS_TW (128 + 3 * 65536)
#define WS_XB 524288ull                       // bf16 x  [8192][1024]  = 16.78 MB
#define WS_H1 (WS_XB + 16777216ull)           // bf16 h1 [16384][2048] = 67.1 MB
#define WS_WT (WS_H1 + 67108864ull)           // bf16 WT (W1T, then reused for W2T) = 33.55 MB
// total ~118 MB

// ---------------- zero out + counts (hipMemsetAsync is NOT graph-capturable) ----
__global__ void zero_kernel(float* __restrict__ out, int* __restrict__ counts) {
  const int i = (blockIdx.x * 256 + threadIdx.x) * 4;
  *(float4*)(out + i) = make_float4(0.f, 0.f, 0.f, 0.f);
  if (blockIdx.x == 0 && threadIdx.x < NE) counts[threadIdx.x] = 0;
}

// ---------------- gating: 1 wave per token ----------------
__global__ void gate_kernel(const float* __restrict__ x, const float* __restrict__ Wg,
                            int* __restrict__ tok_e, float* __restrict__ tok_w,
                            int* __restrict__ counts) {
  const int t = blockIdx.x;
  const int lane = threadIdx.x;
  float acc[NE];
#pragma unroll
  for (int e = 0; e < NE; ++e) acc[e] = 0.f;
  const float* xrow = x + (size_t)t * HD;
#pragma unroll
  for (int i = 0; i < HD / 64; ++i) {
    const int h = i * 64 + lane;
    const float xv = xrow[h];
    const float* wr = Wg + h * NE;
#pragma unroll
    for (int e = 0; e < NE; ++e) acc[e] += xv * wr[e];
  }
#pragma unroll
  for (int off = 32; off >= 1; off >>= 1) {
#pragma unroll
    for (int e = 0; e < NE; ++e) acc[e] += __shfl_xor(acc[e], off);
  }
  if (lane == 0) {
    int i1 = 0;
    float l1 = acc[0];
#pragma unroll
    for (int e = 1; e < NE; ++e)
      if (acc[e] > l1) { l1 = acc[e]; i1 = e; }
    int i2 = -1;
    float l2 = -3.4e38f;
#pragma unroll
    for (int e = 0; e < NE; ++e)
      if (e != i1 && acc[e] > l2) { l2 = acc[e]; i2 = e; }
    const float q = expf(l2 - l1);
    const float w1 = 1.f / (1.f + q);
    tok_e[2 * t] = i1;
    tok_e[2 * t + 1] = i2;
    tok_w[2 * t] = w1;
    tok_w[2 * t + 1] = q * w1;
    atomicAdd(&counts[i1], 1);
    atomicAdd(&counts[i2], 1);
  }
}

__global__ void scan_kernel(const int* __restrict__ counts, int* __restrict__ offsets,
                            int* __restrict__ cursor) {
  if (threadIdx.x == 0) {
    int s = 0;
    for (int e = 0; e < NE; ++e) {
      offsets[e] = s;
      cursor[e] = s;
      s += counts[e];
    }
  }
}

__global__ void scatter_kernel(const int* __restrict__ tok_e, const float* __restrict__ tok_w,
                               int* __restrict__ cursor, int* __restrict__ bucket_tok,
                               float* __restrict__ bucket_w) {
  const int idx = blockIdx.x * 256 + threadIdx.x;
  const int e = tok_e[idx];
  const int pos = atomicAdd(&cursor[e], 1) & (2 * TOKS - 1);
  bucket_tok[pos] = idx >> 1;
  bucket_w[pos] = tok_w[idx];
}

__global__ void convert_x_kernel(const float* __restrict__ x, bf16_t* __restrict__ xb) {
  const int i = (blockIdx.x * 256 + threadIdx.x) * 4;
  const float4 v = *(const float4*)(x + i);
  bf16_t o[4] = {(bf16_t)v.x, (bf16_t)v.y, (bf16_t)v.z, (bf16_t)v.w};
  *(uint2*)(xb + i) = *(uint2*)o;
}

// ---------------- transpose+convert: src [E][K][N] f32 -> dst [E][N][K] bf16 ----
__global__ __launch_bounds__(256) void transpose_convert_kernel(const float* __restrict__ src,
                                                                bf16_t* __restrict__ dst, int K,
                                                                int N) {
  __shared__ float tile[64][65];
  const int e = blockIdx.z;
  const int k0 = blockIdx.x * 64;
  const int n0 = blockIdx.y * 64;
  const float* s = src + (size_t)e * K * N;
  bf16_t* d = dst + (size_t)e * K * N;
  const int t = threadIdx.x;
  const int c = t & 63;
  const int r4 = t >> 6;
#pragma unroll
  for (int p = 0; p < 16; ++p) {
    const int r = p * 4 + r4;
    tile[r][c] = s[(size_t)(k0 + r) * N + n0 + c];
  }
  __syncthreads();
#pragma unroll
  for (int p = 0; p < 16; ++p) {
    const int n = p * 4 + r4;
    d[(size_t)(n0 + n) * K + k0 + c] = (bf16_t)tile[c][n];  // banks (c+n)%32: conflict-free
  }
}

// ---------------- expert GEMMs: 128x128 tile, BK=32, global_load_lds staging ----------------
// A LDS layout [128][32] bf16 un-padded (matches wave-uniform+lane*16 DMA pattern).

__global__ __launch_bounds__(256) void gemm1_kernel(
    const bf16_t* __restrict__ xb, const bf16_t* __restrict__ W1T, const float* __restrict__ b1,
    const int* __restrict__ counts, const int* __restrict__ offsets,
    const int* __restrict__ bucket_tok, bf16_t* __restrict__ h1) {
  const int e = blockIdx.z;
  const int n_e = counts[e];
  const int m_base = blockIdx.x * 128;
  if (m_base >= n_e) return;
  const int n_base = blockIdx.y * 128;
  const int off = offsets[e];

  __shared__ bf16_t As[128 * 32];
  __shared__ bf16_t Bs[128 * 32];

  const int tid = threadIdx.x;
  const int w = tid >> 6;
  const int lane = tid & 63;
  const int quad = lane >> 4;
  const int lrow = lane & 15;

  // staging roles: 4 lanes per row (16B each), 16 rows per instruction, 2 inst/wave/tile
  const int srow = lane >> 2;
  const int kch = (lane & 3) * 8;  // element offset into the 32-wide k chunk
  int r0 = m_base + w * 32 + srow;
  int r1 = r0 + 16;
  if (r0 >= n_e) r0 = n_e - 1;
  if (r1 >= n_e) r1 = n_e - 1;
  const bf16_t* ga0 = xb + (size_t)bucket_tok[off + r0] * HD + kch;
  const bf16_t* ga1 = xb + (size_t)bucket_tok[off + r1] * HD + kch;
  const bf16_t* gb0 = W1T + ((size_t)e * ID + n_base + w * 32 + srow) * HD + kch;
  const bf16_t* gb1 = gb0 + (size_t)16 * HD;
  bf16_t* la0 = As + w * 1024 + lane * 8;
  bf16_t* la1 = la0 + 512;
  bf16_t* lb0 = Bs + w * 1024 + lane * 8;
  bf16_t* lb1 = lb0 + 512;

  f32x4 acc[4][4];
#pragma unroll
  for (int mt = 0; mt < 4; ++mt)
#pragma unroll
    for (int nt = 0; nt < 4; ++nt)
#pragma unroll
      for (int r = 0; r < 4; ++r) acc[mt][nt][r] = 0.f;

  const int mrow = (w & 1) * 64;
  const int nrow = (w >> 1) * 64;

  for (int k0 = 0; k0 < HD; k0 += 32) {
    __syncthreads();
    GLOAD(ga0 + k0, la0);
    GLOAD(ga1 + k0, la1);
    GLOAD(gb0 + k0, lb0);
    GLOAD(gb1 + k0, lb1);
    __syncthreads();  // compiler emits vmcnt(0) drain before barrier

    bf16x8 af[4], bfr[4];
#pragma unroll
    for (int i = 0; i < 4; ++i) {
      af[i] = *(const bf16x8*)(As + (mrow + i * 16 + lrow) * 32 + quad * 8);
      bfr[i] = *(const bf16x8*)(Bs + (nrow + i * 16 + lrow) * 32 + quad * 8);
    }
#pragma unroll
    for (int mt = 0; mt < 4; ++mt)
#pragma unroll
      for (int nt = 0; nt < 4; ++nt)
        acc[mt][nt] =
            __builtin_amdgcn_mfma_f32_16x16x32_bf16(af[mt], bfr[nt], acc[mt][nt], 0, 0, 0);
  }

#pragma unroll
  for (int mt = 0; mt < 4; ++mt) {
#pragma unroll
    for (int r = 0; r < 4; ++r) {
      const int gm = m_base + mrow + mt * 16 + quad * 4 + r;
      if (gm < n_e) {
        bf16_t* orow = h1 + (size_t)(off + gm) * ID;
#pragma unroll
        for (int nt = 0; nt < 4; ++nt) {
          const int gi = n_base + nrow + nt * 16 + lrow;
          float v = acc[mt][nt][r] + b1[e * ID + gi];
          v = 0.5f * v * (1.f + erff(v * 0.70710678118654752f));  // exact-erf GELU
          orow[gi] = (bf16_t)v;
        }
      }
    }
  }
}

__global__ __launch_bounds__(256) void gemm2_kernel(
    const bf16_t* __restrict__ h1, const bf16_t* __restrict__ W2T, const float* __restrict__ b2,
    const int* __restrict__ counts, const int* __restrict__ offsets,
    const int* __restrict__ bucket_tok, const float* __restrict__ bucket_w,
    float* __restrict__ out) {
  const int e = blockIdx.z;
  const int n_e = counts[e];
  const int m_base = blockIdx.x * 128;
  if (m_base >= n_e) return;
  const int n_base = blockIdx.y * 128;
  const int off = offsets[e];

  __shared__ bf16_t As[128 * 32];
  __shared__ bf16_t Bs[128 * 32];

  const int tid = threadIdx.x;
  const int w = tid >> 6;
  const int lane = tid & 63;
  const int quad = lane >> 4;
  const int lrow = lane & 15;

  const int srow = lane >> 2;
  const int kch = (lane & 3) * 8;
  int r0 = m_base + w * 32 + srow;
  int r1 = r0 + 16;
  if (r0 >= n_e) r0 = n_e - 1;
  if (r1 >= n_e) r1 = n_e - 1;
  const bf16_t* ga0 = h1 + (size_t)(off + r0) * ID + kch;
  const bf16_t* ga1 = h1 + (size_t)(off + r1) * ID + kch;
  const bf16_t* gb0 = W2T + ((size_t)e * HD + n_base + w * 32 + srow) * ID + kch;
  const bf16_t* gb1 = gb0 + (size_t)16 * ID;
  bf16_t* la0 = As + w * 1024 + lane * 8;
  bf16_t* la1 = la0 + 512;
  bf16_t* lb0 = Bs + w * 1024 + lane * 8;
  bf16_t* lb1 = lb0 + 512;

  f32x4 acc[4][4];
#pragma unroll
  for (int mt = 0; mt < 4; ++mt)
#pragma unroll
    for (int nt = 0; nt < 4; ++nt)
#pragma unroll
      for (int r = 0; r < 4; ++r) acc[mt][nt][r] = 0.f;

  const int mrow = (w & 1) * 64;
  const int nrow = (w >> 1) * 64;

  for (int k0 = 0; k0 < ID; k0 += 32) {
    __syncthreads();
    GLOAD(ga0 + k0, la0);
    GLOAD(ga1 + k0, la1);
    GLOAD(gb0 + k0, lb0);
    GLOAD(gb1 + k0, lb1);
    __syncthreads();

    bf16x8 af[4], bfr[4];
#pragma unroll
    for (int i = 0; i < 4; ++i) {
      af[i] = *(const bf16x8*)(As + (mrow + i * 16 + lrow) * 32 + quad * 8);
      bfr[i] = *(const bf16x8*)(Bs + (nrow + i * 16 + lrow) * 32 + quad * 8);
    }
#pragma unroll
    for (int mt = 0; mt < 4; ++mt)
#pragma unroll
      for (int nt = 0; nt < 4; ++nt)
        acc[mt][nt] =
            __builtin_amdgcn_mfma_f32_16x16x32_bf16(af[mt], bfr[nt], acc[mt][nt], 0, 0, 0);
  }

#pragma unroll
  for (int mt = 0; mt < 4; ++mt) {
#pragma unroll
    for (int r = 0; r < 4; ++r) {
      const int gm = m_base + mrow + mt * 16 + quad * 4 + r;
      if (gm < n_e) {
        const int pos = off + gm;
        const int tokid = bucket_tok[pos];
        const float wgt = bucket_w[pos];
        float* orow = out + (size_t)tokid * HD;
#pragma unroll
        for (int nt = 0; nt < 4; ++nt) {
          const int gh = n_base + nrow + nt * 16 + lrow;
          const float v = acc[mt][nt][r] + b2[e * HD + gh];
          atomicAdd(orow + gh, wgt * v);
        }
      }
    }
  }
}

extern "C" void kernel_launch(void* const* d_in, const int* in_sizes, int n_in,
                              void* d_out, int out_size, void* d_ws, size_t ws_size,
                              hipStream_t stream) {
  const float* x = (const float*)d_in[0];
  const float* Wg = (const float*)d_in[1];
  const float* W1 = (const float*)d_in[2];
  const float* b1 = (const float*)d_in[3];
  const float* W2 = (const float*)d_in[4];
  const float* b2 = (const float*)d_in[5];
  float* out = (float*)d_out;
  char* ws = (char*)d_ws;

  int* counts = (int*)(ws + WS_COUNTS);
  int* offsets = (int*)(ws + WS_OFFSETS);
  int* cursor = (int*)(ws + WS_CURSOR);
  int* bucket_tok = (int*)(ws + WS_BTOK);
  float* bucket_w = (float*)(ws + WS_BW);
  int* tok_e = (int*)(ws + WS_TE);
  float* tok_w = (float*)(ws + WS_TW);
  bf16_t* xb = (bf16_t*)(ws + WS_XB);
  bf16_t* h1 = (bf16_t*)(ws + WS_H1);
  bf16_t* WT = (bf16_t*)(ws + WS_WT);  // W1T for gemm1, then overwritten with W2T

  zero_kernel<<<(TOKS * HD / 4) / 256, 256, 0, stream>>>(out, counts);
  gate_kernel<<<TOKS, 64, 0, stream>>>(x, Wg, tok_e, tok_w, counts);
  scan_kernel<<<1, 64, 0, stream>>>(counts, offsets, cursor);
  scatter_kernel<<<TOKS * 2 / 256, 256, 0, stream>>>(tok_e, tok_w, cursor, bucket_tok, bucket_w);
  convert_x_kernel<<<TOKS * HD / 4 / 256, 256, 0, stream>>>(x, xb);
  // W1 [E][HD][ID] -> W1T [E][ID][HD]
  transpose_convert_kernel<<<dim3(HD / 64, ID / 64, NE), 256, 0, stream>>>(W1, WT, HD, ID);
  gemm1_kernel<<<dim3(TOKS / 128, ID / 128, NE), 256, 0, stream>>>(xb, WT, b1, counts, offsets,
                                                                   bucket_tok, h1);
  // W2 [E][ID][HD] -> W2T [E][HD][ID] (reuses WT buffer; stream-serialized after gemm1)
  transpose_convert_kernel<<<dim3(ID / 64, HD / 64, NE), 256, 0, stream>>>(W2, WT, ID, HD);
  gemm2_kernel<<<dim3(TOKS / 128, HD / 128, NE), 256, 0, stream>>>(h1, WT, b2, counts, offsets,
                                                                   bucket_tok, bucket_w, out);
}

// Round 4
// 811.472 us; speedup vs baseline: 1.4895x; 1.1312x over previous
//
#include <hip/hip_runtime.h>
#include <math.h>

#define TOKS 8192
#define HD 1024
#define ID 2048
#define NE 8

typedef __bf16 bf16_t;
typedef __bf16 bf16x8 __attribute__((ext_vector_type(8)));
typedef float f32x4 __attribute__((ext_vector_type(4)));

// async global->LDS, 16 bytes per lane. LDS dest: wave-uniform base + lane*16.
#define GLOAD(gp, lp)                                                \
  __builtin_amdgcn_global_load_lds(                                  \
      (const __attribute__((address_space(1))) void*)(gp),           \
      (__attribute__((address_space(3))) void*)(lp), 16, 0, 0)

// ---------------- workspace layout (bytes) ----------------
#define WS_COUNTS 0
#define WS_OFFSETS 32
#define WS_CURSOR 64
#define WS_BTOK 128
#define WS_BW (128 + 65536)
#define WS_TE (128 + 2 * 65536)
#define WS_TW (128 + 3 * 65536)
#define WS_WL 263168ull                       // work-list: wl_e[160], wl_m[160], n_work
#define WS_XB 524288ull                       // bf16 x  [8192][1024]  = 16.78 MB
#define WS_H1 (WS_XB + 16777216ull)           // bf16 h1 [16384][2048] = 67.1 MB
#define WS_WT (WS_H1 + 67108864ull)           // bf16 WT (W1T then W2T) = 33.55 MB

#define MAXWL 144

// ---------------- zero out + counts (hipMemsetAsync is NOT graph-capturable) ----
__global__ void zero_kernel(float* __restrict__ out, int* __restrict__ counts) {
  const int i = (blockIdx.x * 256 + threadIdx.x) * 4;
  *(float4*)(out + i) = make_float4(0.f, 0.f, 0.f, 0.f);
  if (blockIdx.x == 0 && threadIdx.x < NE) counts[threadIdx.x] = 0;
}

// ---------------- gating: 1 wave per token ----------------
__global__ void gate_kernel(const float* __restrict__ x, const float* __restrict__ Wg,
                            int* __restrict__ tok_e, float* __restrict__ tok_w,
                            int* __restrict__ counts) {
  const int t = blockIdx.x;
  const int lane = threadIdx.x;
  float acc[NE];
#pragma unroll
  for (int e = 0; e < NE; ++e) acc[e] = 0.f;
  const float* xrow = x + (size_t)t * HD;
#pragma unroll
  for (int i = 0; i < HD / 64; ++i) {
    const int h = i * 64 + lane;
    const float xv = xrow[h];
    const float* wr = Wg + h * NE;
#pragma unroll
    for (int e = 0; e < NE; ++e) acc[e] += xv * wr[e];
  }
#pragma unroll
  for (int off = 32; off >= 1; off >>= 1) {
#pragma unroll
    for (int e = 0; e < NE; ++e) acc[e] += __shfl_xor(acc[e], off);
  }
  if (lane == 0) {
    int i1 = 0;
    float l1 = acc[0];
#pragma unroll
    for (int e = 1; e < NE; ++e)
      if (acc[e] > l1) { l1 = acc[e]; i1 = e; }
    int i2 = -1;
    float l2 = -3.4e38f;
#pragma unroll
    for (int e = 0; e < NE; ++e)
      if (e != i1 && acc[e] > l2) { l2 = acc[e]; i2 = e; }
    const float q = expf(l2 - l1);
    const float w1 = 1.f / (1.f + q);
    tok_e[2 * t] = i1;
    tok_e[2 * t + 1] = i2;
    tok_w[2 * t] = w1;
    tok_w[2 * t + 1] = q * w1;
    atomicAdd(&counts[i1], 1);
    atomicAdd(&counts[i2], 1);
  }
}

// scan + build dense (expert, m_tile) work-list
__global__ void scan_kernel(const int* __restrict__ counts, int* __restrict__ offsets,
                            int* __restrict__ cursor, int* __restrict__ wl_e,
                            int* __restrict__ wl_m, int* __restrict__ n_work) {
  if (threadIdx.x == 0) {
    int s = 0, idx = 0;
    for (int e = 0; e < NE; ++e) {
      offsets[e] = s;
      cursor[e] = s;
      for (int m = 0; m < counts[e] && idx < MAXWL; m += 128) {
        wl_e[idx] = e;
        wl_m[idx] = m;
        ++idx;
      }
      s += counts[e];
    }
    *n_work = idx;
  }
}

__global__ void scatter_kernel(const int* __restrict__ tok_e, const float* __restrict__ tok_w,
                               int* __restrict__ cursor, int* __restrict__ bucket_tok,
                               float* __restrict__ bucket_w) {
  const int idx = blockIdx.x * 256 + threadIdx.x;
  const int e = tok_e[idx];
  const int pos = atomicAdd(&cursor[e], 1) & (2 * TOKS - 1);
  bucket_tok[pos] = idx >> 1;
  bucket_w[pos] = tok_w[idx];
}

__global__ void convert_x_kernel(const float* __restrict__ x, bf16_t* __restrict__ xb) {
  const int i = (blockIdx.x * 256 + threadIdx.x) * 4;
  const float4 v = *(const float4*)(x + i);
  bf16_t o[4] = {(bf16_t)v.x, (bf16_t)v.y, (bf16_t)v.z, (bf16_t)v.w};
  *(uint2*)(xb + i) = *(uint2*)o;
}

// ---------------- transpose+convert: src [E][K][N] f32 -> dst [E][N][K] bf16 ----
__global__ __launch_bounds__(256) void transpose_convert_kernel(const float* __restrict__ src,
                                                                bf16_t* __restrict__ dst, int K,
                                                                int N) {
  __shared__ float tile[64][65];
  const int e = blockIdx.z;
  const int k0 = blockIdx.x * 64;
  const int n0 = blockIdx.y * 64;
  const float* s = src + (size_t)e * K * N;
  bf16_t* d = dst + (size_t)e * K * N;
  const int t = threadIdx.x;
  const int c = t & 63;
  const int r4 = t >> 6;
#pragma unroll
  for (int p = 0; p < 16; ++p) {
    const int r = p * 4 + r4;
    tile[r][c] = s[(size_t)(k0 + r) * N + n0 + c];
  }
  __syncthreads();
  // vectorized write: each thread emits 4 consecutive k (8B) of one n-row
  const int kc = t & 15;   // k-chunk of 4
  const int nb = t >> 4;   // 0..15
#pragma unroll
  for (int p = 0; p < 4; ++p) {
    const int n = p * 16 + nb;
    bf16_t o[4];
#pragma unroll
    for (int j = 0; j < 4; ++j) o[j] = (bf16_t)tile[kc * 4 + j][n];
    *(uint2*)(d + (size_t)(n0 + n) * K + k0 + kc * 4) = *(uint2*)o;
  }
}

// ---------------- expert GEMMs: 128x128 tile, BK=32, double-buffered DMA staging ----------------

__global__ __launch_bounds__(256) void gemm1_kernel(
    const bf16_t* __restrict__ xb, const bf16_t* __restrict__ W1T, const float* __restrict__ b1,
    const int* __restrict__ counts, const int* __restrict__ offsets,
    const int* __restrict__ bucket_tok, const int* __restrict__ wl_e,
    const int* __restrict__ wl_m, const int* __restrict__ n_work, bf16_t* __restrict__ h1) {
  const int widx = blockIdx.x;
  if (widx >= *n_work) return;
  const int e = wl_e[widx];
  const int m_base = wl_m[widx];
  const int n_e = counts[e];
  const int n_base = blockIdx.y * 128;
  const int off = offsets[e];

  __shared__ bf16_t As[2][128 * 32];
  __shared__ bf16_t Bs[2][128 * 32];

  const int tid = threadIdx.x;
  const int w = tid >> 6;
  const int lane = tid & 63;
  const int quad = lane >> 4;
  const int lrow = lane & 15;

  const int srow = lane >> 2;
  const int kch = (lane & 3) * 8;
  int r0 = m_base + w * 32 + srow;
  int r1 = r0 + 16;
  if (r0 >= n_e) r0 = n_e - 1;
  if (r1 >= n_e) r1 = n_e - 1;
  const bf16_t* ga0 = xb + (size_t)bucket_tok[off + r0] * HD + kch;
  const bf16_t* ga1 = xb + (size_t)bucket_tok[off + r1] * HD + kch;
  const bf16_t* gb0 = W1T + ((size_t)e * ID + n_base + w * 32 + srow) * HD + kch;
  const bf16_t* gb1 = gb0 + (size_t)16 * HD;
  const int lofs0 = w * 1024 + lane * 8;
  const int lofs1 = lofs0 + 512;

  f32x4 acc[4][4];
#pragma unroll
  for (int mt = 0; mt < 4; ++mt)
#pragma unroll
    for (int nt = 0; nt < 4; ++nt)
#pragma unroll
      for (int r = 0; r < 4; ++r) acc[mt][nt][r] = 0.f;

  const int mrow = (w & 1) * 64;
  const int nrow = (w >> 1) * 64;

  // prologue: stage tile 0 into buffer 0
  GLOAD(ga0, &As[0][lofs0]);
  GLOAD(ga1, &As[0][lofs1]);
  GLOAD(gb0, &Bs[0][lofs0]);
  GLOAD(gb1, &Bs[0][lofs1]);

#define NT1 (HD / 32)
  for (int kt = 0; kt < NT1; ++kt) {
    __syncthreads();  // drains own DMA (tile kt) + guards buffer reuse
    const int cur = kt & 1;
    if (kt + 1 < NT1) {  // prefetch tile kt+1 into other buffer; overlaps compute below
      const int nxt = cur ^ 1;
      const size_t ko = (size_t)(kt + 1) * 32;
      GLOAD(ga0 + ko, &As[nxt][lofs0]);
      GLOAD(ga1 + ko, &As[nxt][lofs1]);
      GLOAD(gb0 + ko, &Bs[nxt][lofs0]);
      GLOAD(gb1 + ko, &Bs[nxt][lofs1]);
    }
    bf16x8 af[4], bfr[4];
#pragma unroll
    for (int i = 0; i < 4; ++i) {
      af[i] = *(const bf16x8*)(&As[cur][(mrow + i * 16 + lrow) * 32 + quad * 8]);
      bfr[i] = *(const bf16x8*)(&Bs[cur][(nrow + i * 16 + lrow) * 32 + quad * 8]);
    }
#pragma unroll
    for (int mt = 0; mt < 4; ++mt)
#pragma unroll
      for (int nt = 0; nt < 4; ++nt)
        acc[mt][nt] =
            __builtin_amdgcn_mfma_f32_16x16x32_bf16(af[mt], bfr[nt], acc[mt][nt], 0, 0, 0);
  }

#pragma unroll
  for (int mt = 0; mt < 4; ++mt) {
#pragma unroll
    for (int r = 0; r < 4; ++r) {
      const int gm = m_base + mrow + mt * 16 + quad * 4 + r;
      if (gm < n_e) {
        bf16_t* orow = h1 + (size_t)(off + gm) * ID;
#pragma unroll
        for (int nt = 0; nt < 4; ++nt) {
          const int gi = n_base + nrow + nt * 16 + lrow;
          float v = acc[mt][nt][r] + b1[e * ID + gi];
          v = 0.5f * v * (1.f + erff(v * 0.70710678118654752f));  // exact-erf GELU
          orow[gi] = (bf16_t)v;
        }
      }
    }
  }
}

__global__ __launch_bounds__(256) void gemm2_kernel(
    const bf16_t* __restrict__ h1, const bf16_t* __restrict__ W2T, const float* __restrict__ b2,
    const int* __restrict__ counts, const int* __restrict__ offsets,
    const int* __restrict__ bucket_tok, const float* __restrict__ bucket_w,
    const int* __restrict__ wl_e, const int* __restrict__ wl_m, const int* __restrict__ n_work,
    float* __restrict__ out) {
  const int widx = blockIdx.x;
  if (widx >= *n_work) return;
  const int e = wl_e[widx];
  const int m_base = wl_m[widx];
  const int n_e = counts[e];
  const int n_base = blockIdx.y * 128;
  const int split = blockIdx.z;            // split-K: 2 x 1024
  const int kbase = split * (ID / 2);
  const int off = offsets[e];

  __shared__ bf16_t As[2][128 * 32];
  __shared__ bf16_t Bs[2][128 * 32];

  const int tid = threadIdx.x;
  const int w = tid >> 6;
  const int lane = tid & 63;
  const int quad = lane >> 4;
  const int lrow = lane & 15;

  const int srow = lane >> 2;
  const int kch = (lane & 3) * 8;
  int r0 = m_base + w * 32 + srow;
  int r1 = r0 + 16;
  if (r0 >= n_e) r0 = n_e - 1;
  if (r1 >= n_e) r1 = n_e - 1;
  const bf16_t* ga0 = h1 + (size_t)(off + r0) * ID + kbase + kch;
  const bf16_t* ga1 = h1 + (size_t)(off + r1) * ID + kbase + kch;
  const bf16_t* gb0 = W2T + ((size_t)e * HD + n_base + w * 32 + srow) * ID + kbase + kch;
  const bf16_t* gb1 = gb0 + (size_t)16 * ID;
  const int lofs0 = w * 1024 + lane * 8;
  const int lofs1 = lofs0 + 512;

  f32x4 acc[4][4];
#pragma unroll
  for (int mt = 0; mt < 4; ++mt)
#pragma unroll
    for (int nt = 0; nt < 4; ++nt)
#pragma unroll
      for (int r = 0; r < 4; ++r) acc[mt][nt][r] = 0.f;

  const int mrow = (w & 1) * 64;
  const int nrow = (w >> 1) * 64;

  GLOAD(ga0, &As[0][lofs0]);
  GLOAD(ga1, &As[0][lofs1]);
  GLOAD(gb0, &Bs[0][lofs0]);
  GLOAD(gb1, &Bs[0][lofs1]);

#define NT2 (ID / 2 / 32)
  for (int kt = 0; kt < NT2; ++kt) {
    __syncthreads();
    const int cur = kt & 1;
    if (kt + 1 < NT2) {
      const int nxt = cur ^ 1;
      const size_t ko = (size_t)(kt + 1) * 32;
      GLOAD(ga0 + ko, &As[nxt][lofs0]);
      GLOAD(ga1 + ko, &As[nxt][lofs1]);
      GLOAD(gb0 + ko, &Bs[nxt][lofs0]);
      GLOAD(gb1 + ko, &Bs[nxt][lofs1]);
    }
    bf16x8 af[4], bfr[4];
#pragma unroll
    for (int i = 0; i < 4; ++i) {
      af[i] = *(const bf16x8*)(&As[cur][(mrow + i * 16 + lrow) * 32 + quad * 8]);
      bfr[i] = *(const bf16x8*)(&Bs[cur][(nrow + i * 16 + lrow) * 32 + quad * 8]);
    }
#pragma unroll
    for (int mt = 0; mt < 4; ++mt)
#pragma unroll
      for (int nt = 0; nt < 4; ++nt)
        acc[mt][nt] =
            __builtin_amdgcn_mfma_f32_16x16x32_bf16(af[mt], bfr[nt], acc[mt][nt], 0, 0, 0);
  }

#pragma unroll
  for (int mt = 0; mt < 4; ++mt) {
#pragma unroll
    for (int r = 0; r < 4; ++r) {
      const int gm = m_base + mrow + mt * 16 + quad * 4 + r;
      if (gm < n_e) {
        const int pos = off + gm;
        const int tokid = bucket_tok[pos];
        const float wgt = bucket_w[pos];
        float* orow = out + (size_t)tokid * HD;
#pragma unroll
        for (int nt = 0; nt < 4; ++nt) {
          const int gh = n_base + nrow + nt * 16 + lrow;
          float v = acc[mt][nt][r];
          if (split == 0) v += b2[e * HD + gh];  // bias once
          atomicAdd(orow + gh, wgt * v);
        }
      }
    }
  }
}

extern "C" void kernel_launch(void* const* d_in, const int* in_sizes, int n_in,
                              void* d_out, int out_size, void* d_ws, size_t ws_size,
                              hipStream_t stream) {
  const float* x = (const float*)d_in[0];
  const float* Wg = (const float*)d_in[1];
  const float* W1 = (const float*)d_in[2];
  const float* b1 = (const float*)d_in[3];
  const float* W2 = (const float*)d_in[4];
  const float* b2 = (const float*)d_in[5];
  float* out = (float*)d_out;
  char* ws = (char*)d_ws;

  int* counts = (int*)(ws + WS_COUNTS);
  int* offsets = (int*)(ws + WS_OFFSETS);
  int* cursor = (int*)(ws + WS_CURSOR);
  int* bucket_tok = (int*)(ws + WS_BTOK);
  float* bucket_w = (float*)(ws + WS_BW);
  int* tok_e = (int*)(ws + WS_TE);
  float* tok_w = (float*)(ws + WS_TW);
  int* wl_e = (int*)(ws + WS_WL);
  int* wl_m = wl_e + MAXWL;
  int* n_work = wl_m + MAXWL;
  bf16_t* xb = (bf16_t*)(ws + WS_XB);
  bf16_t* h1 = (bf16_t*)(ws + WS_H1);
  bf16_t* WT = (bf16_t*)(ws + WS_WT);

  zero_kernel<<<(TOKS * HD / 4) / 256, 256, 0, stream>>>(out, counts);
  gate_kernel<<<TOKS, 64, 0, stream>>>(x, Wg, tok_e, tok_w, counts);
  scan_kernel<<<1, 64, 0, stream>>>(counts, offsets, cursor, wl_e, wl_m, n_work);
  scatter_kernel<<<TOKS * 2 / 256, 256, 0, stream>>>(tok_e, tok_w, cursor, bucket_tok, bucket_w);
  convert_x_kernel<<<TOKS * HD / 4 / 256, 256, 0, stream>>>(x, xb);
  transpose_convert_kernel<<<dim3(HD / 64, ID / 64, NE), 256, 0, stream>>>(W1, WT, HD, ID);
  gemm1_kernel<<<dim3(MAXWL, ID / 128), 256, 0, stream>>>(xb, WT, b1, counts, offsets, bucket_tok,
                                                          wl_e, wl_m, n_work, h1);
  transpose_convert_kernel<<<dim3(ID / 64, HD / 64, NE), 256, 0, stream>>>(W2, WT, ID, HD);
  gemm2_kernel<<<dim3(MAXWL, HD / 128, 2), 256, 0, stream>>>(h1, WT, b2, counts, offsets,
                                                             bucket_tok, bucket_w, wl_e, wl_m,
                                                             n_work, out);
}

// Round 5
// 808.248 us; speedup vs baseline: 1.4954x; 1.0040x over previous
//
#include <hip/hip_runtime.h>
#include <math.h>

#define TOKS 8192
#define HD 1024
#define ID 2048
#define NE 8

typedef __bf16 bf16_t;
typedef __bf16 bf16x8 __attribute__((ext_vector_type(8)));
typedef float f32x4 __attribute__((ext_vector_type(4)));

// async global->LDS, 16 bytes per lane. LDS dest: wave-uniform base + lane*16.
#define GLOAD(gp, lp)                                                \
  __builtin_amdgcn_global_load_lds(                                  \
      (const __attribute__((address_space(1))) void*)(gp),           \
      (__attribute__((address_space(3))) void*)(lp), 16, 0, 0)

// ---------------- workspace layout (bytes) ----------------
#define WS_COUNTS 0
#define WS_OFFSETS 32
#define WS_CURSOR 64
#define WS_BTOK 128
#define WS_BW (128 + 65536)
#define WS_TE (128 + 2 * 65536)
#define WS_TW (128 + 3 * 65536)
#define WS_WL 263168ull
#define WS_XB 524288ull                       // bf16 x  [8192][1024]  = 16.78 MB
#define WS_H1 (WS_XB + 16777216ull)           // bf16 h1 [16384][2048] = 67.1 MB
#define WS_WT (WS_H1 + 67108864ull)           // bf16 WT (W1T then W2T) = 33.55 MB

#define MAXWL 144

// ---------------- zero out + counts (hipMemsetAsync is NOT graph-capturable) ----
__global__ void zero_kernel(float* __restrict__ out, int* __restrict__ counts) {
  const int i = (blockIdx.x * 256 + threadIdx.x) * 4;
  *(float4*)(out + i) = make_float4(0.f, 0.f, 0.f, 0.f);
  if (blockIdx.x == 0 && threadIdx.x < NE) counts[threadIdx.x] = 0;
}

// ---------------- gating (+ fused x -> bf16 conversion): 1 wave per token ----------------
__global__ void gate_kernel(const float* __restrict__ x, const float* __restrict__ Wg,
                            bf16_t* __restrict__ xb, int* __restrict__ tok_e,
                            float* __restrict__ tok_w, int* __restrict__ counts) {
  const int t = blockIdx.x;
  const int lane = threadIdx.x;
  const float* xrow = x + (size_t)t * HD;
  bf16_t* xbrow = xb + (size_t)t * HD;
  float acc[NE];
#pragma unroll
  for (int e = 0; e < NE; ++e) acc[e] = 0.f;
#pragma unroll
  for (int p = 0; p < 4; ++p) {
    const int h0 = p * 256 + lane * 4;
    const float4 v = *(const float4*)(xrow + h0);
    const float vv[4] = {v.x, v.y, v.z, v.w};
    bf16_t o[4] = {(bf16_t)v.x, (bf16_t)v.y, (bf16_t)v.z, (bf16_t)v.w};
    *(uint2*)(xbrow + h0) = *(uint2*)o;
#pragma unroll
    for (int j = 0; j < 4; ++j) {
      const float xv = vv[j];
      const float* wr = Wg + (h0 + j) * NE;
#pragma unroll
      for (int e = 0; e < NE; ++e) acc[e] += xv * wr[e];
    }
  }
#pragma unroll
  for (int off = 32; off >= 1; off >>= 1) {
#pragma unroll
    for (int e = 0; e < NE; ++e) acc[e] += __shfl_xor(acc[e], off);
  }
  if (lane == 0) {
    int i1 = 0;
    float l1 = acc[0];
#pragma unroll
    for (int e = 1; e < NE; ++e)
      if (acc[e] > l1) { l1 = acc[e]; i1 = e; }
    int i2 = -1;
    float l2 = -3.4e38f;
#pragma unroll
    for (int e = 0; e < NE; ++e)
      if (e != i1 && acc[e] > l2) { l2 = acc[e]; i2 = e; }
    const float q = expf(l2 - l1);
    const float w1 = 1.f / (1.f + q);
    tok_e[2 * t] = i1;
    tok_e[2 * t + 1] = i2;
    tok_w[2 * t] = w1;
    tok_w[2 * t + 1] = q * w1;
    atomicAdd(&counts[i1], 1);
    atomicAdd(&counts[i2], 1);
  }
}

// scan + build dense (expert, m_tile) work-list
__global__ void scan_kernel(const int* __restrict__ counts, int* __restrict__ offsets,
                            int* __restrict__ cursor, int* __restrict__ wl_e,
                            int* __restrict__ wl_m, int* __restrict__ n_work) {
  if (threadIdx.x == 0) {
    int s = 0, idx = 0;
    for (int e = 0; e < NE; ++e) {
      offsets[e] = s;
      cursor[e] = s;
      for (int m = 0; m < counts[e] && idx < MAXWL; m += 128) {
        wl_e[idx] = e;
        wl_m[idx] = m;
        ++idx;
      }
      s += counts[e];
    }
    *n_work = idx;
  }
}

__global__ void scatter_kernel(const int* __restrict__ tok_e, const float* __restrict__ tok_w,
                               int* __restrict__ cursor, int* __restrict__ bucket_tok,
                               float* __restrict__ bucket_w) {
  const int idx = blockIdx.x * 256 + threadIdx.x;
  const int e = tok_e[idx];
  const int pos = atomicAdd(&cursor[e], 1) & (2 * TOKS - 1);
  bucket_tok[pos] = idx >> 1;
  bucket_w[pos] = tok_w[idx];
}

// ---------------- transpose+convert: src [E][K][N] f32 -> dst [E][N][K] bf16 ----
__global__ __launch_bounds__(256) void transpose_convert_kernel(const float* __restrict__ src,
                                                                bf16_t* __restrict__ dst, int K,
                                                                int N) {
  __shared__ float tile[64][65];
  const int e = blockIdx.z;
  const int k0 = blockIdx.x * 64;
  const int n0 = blockIdx.y * 64;
  const float* s = src + (size_t)e * K * N;
  bf16_t* d = dst + (size_t)e * K * N;
  const int t = threadIdx.x;
  const int c = t & 63;
  const int r4 = t >> 6;
#pragma unroll
  for (int p = 0; p < 16; ++p) {
    const int r = p * 4 + r4;
    tile[r][c] = s[(size_t)(k0 + r) * N + n0 + c];
  }
  __syncthreads();
  // 16B/lane writes: thread handles 8 consecutive k of one n-row
  const int kc = t & 7;    // k-chunk of 8
  const int nb = t >> 3;   // 0..31
#pragma unroll
  for (int p = 0; p < 2; ++p) {
    const int n = p * 32 + nb;
    bf16_t o[8];
#pragma unroll
    for (int j = 0; j < 8; ++j) o[j] = (bf16_t)tile[kc * 8 + j][n];
    *(uint4*)(d + (size_t)(n0 + n) * K + k0 + kc * 8) = *(uint4*)o;
  }
}

// ---------------- expert GEMMs: 128x64 block tile, 4 waves x (32x64), BK=32, dbuf DMA ----

__global__ __launch_bounds__(256, 4) void gemm1_kernel(
    const bf16_t* __restrict__ xb, const bf16_t* __restrict__ W1T, const float* __restrict__ b1,
    const int* __restrict__ counts, const int* __restrict__ offsets,
    const int* __restrict__ bucket_tok, const int* __restrict__ wl_e,
    const int* __restrict__ wl_m, const int* __restrict__ n_work, bf16_t* __restrict__ h1) {
  const int widx = blockIdx.x;
  if (widx >= *n_work) return;
  const int e = wl_e[widx];
  const int m_base = wl_m[widx];
  const int n_e = counts[e];
  const int n_base = blockIdx.y * 64;
  const int off = offsets[e];

  __shared__ bf16_t As[2][128 * 32];
  __shared__ bf16_t Bs[2][64 * 32];

  const int tid = threadIdx.x;
  const int w = tid >> 6;
  const int lane = tid & 63;
  const int quad = lane >> 4;
  const int lrow = lane & 15;

  const int srow = lane >> 2;        // 16 rows per GLOAD
  const int kch = (lane & 3) * 8;
  int r0 = m_base + w * 32 + srow;
  int r1 = r0 + 16;
  if (r0 >= n_e) r0 = n_e - 1;
  if (r1 >= n_e) r1 = n_e - 1;
  const bf16_t* ga0 = xb + (size_t)bucket_tok[off + r0] * HD + kch;
  const bf16_t* ga1 = xb + (size_t)bucket_tok[off + r1] * HD + kch;
  const bf16_t* gb0 = W1T + ((size_t)e * ID + n_base + w * 16 + srow) * HD + kch;
  const int laofs0 = w * 1024 + lane * 8;   // rows w*32.. in [128][32]
  const int laofs1 = laofs0 + 512;          // +16 rows
  const int lbofs = w * 512 + lane * 8;     // rows w*16.. in [64][32]

  f32x4 acc[2][4];
#pragma unroll
  for (int mt = 0; mt < 2; ++mt)
#pragma unroll
    for (int nt = 0; nt < 4; ++nt)
#pragma unroll
      for (int r = 0; r < 4; ++r) acc[mt][nt][r] = 0.f;

  // prologue: stage tile 0 into buffer 0
  GLOAD(ga0, &As[0][laofs0]);
  GLOAD(ga1, &As[0][laofs1]);
  GLOAD(gb0, &Bs[0][lbofs]);

#define NT1 (HD / 32)
  for (int kt = 0; kt < NT1; ++kt) {
    __syncthreads();  // drains own DMA (tile kt) + guards buffer reuse
    const int cur = kt & 1;
    if (kt + 1 < NT1) {
      const int nxt = cur ^ 1;
      const size_t ko = (size_t)(kt + 1) * 32;
      GLOAD(ga0 + ko, &As[nxt][laofs0]);
      GLOAD(ga1 + ko, &As[nxt][laofs1]);
      GLOAD(gb0 + ko, &Bs[nxt][lbofs]);
    }
    bf16x8 af[2], bfr[4];
#pragma unroll
    for (int i = 0; i < 2; ++i)
      af[i] = *(const bf16x8*)(&As[cur][(w * 32 + i * 16 + lrow) * 32 + quad * 8]);
#pragma unroll
    for (int i = 0; i < 4; ++i)
      bfr[i] = *(const bf16x8*)(&Bs[cur][(i * 16 + lrow) * 32 + quad * 8]);
#pragma unroll
    for (int mt = 0; mt < 2; ++mt)
#pragma unroll
      for (int nt = 0; nt < 4; ++nt)
        acc[mt][nt] =
            __builtin_amdgcn_mfma_f32_16x16x32_bf16(af[mt], bfr[nt], acc[mt][nt], 0, 0, 0);
  }

#pragma unroll
  for (int mt = 0; mt < 2; ++mt) {
#pragma unroll
    for (int r = 0; r < 4; ++r) {
      const int gm = m_base + w * 32 + mt * 16 + quad * 4 + r;
      if (gm < n_e) {
        bf16_t* orow = h1 + (size_t)(off + gm) * ID;
#pragma unroll
        for (int nt = 0; nt < 4; ++nt) {
          const int gi = n_base + nt * 16 + lrow;
          float v = acc[mt][nt][r] + b1[e * ID + gi];
          v = 0.5f * v * (1.f + erff(v * 0.70710678118654752f));  // exact-erf GELU
          orow[gi] = (bf16_t)v;
        }
      }
    }
  }
}

__global__ __launch_bounds__(256, 4) void gemm2_kernel(
    const bf16_t* __restrict__ h1, const bf16_t* __restrict__ W2T, const float* __restrict__ b2,
    const int* __restrict__ counts, const int* __restrict__ offsets,
    const int* __restrict__ bucket_tok, const float* __restrict__ bucket_w,
    const int* __restrict__ wl_e, const int* __restrict__ wl_m, const int* __restrict__ n_work,
    float* __restrict__ out) {
  const int widx = blockIdx.x;
  if (widx >= *n_work) return;
  const int e = wl_e[widx];
  const int m_base = wl_m[widx];
  const int n_e = counts[e];
  const int n_base = blockIdx.y * 64;
  const int split = blockIdx.z;            // split-K: 2 x 1024
  const int kbase = split * (ID / 2);
  const int off = offsets[e];

  __shared__ bf16_t As[2][128 * 32];
  __shared__ bf16_t Bs[2][64 * 32];

  const int tid = threadIdx.x;
  const int w = tid >> 6;
  const int lane = tid & 63;
  const int quad = lane >> 4;
  const int lrow = lane & 15;

  const int srow = lane >> 2;
  const int kch = (lane & 3) * 8;
  int r0 = m_base + w * 32 + srow;
  int r1 = r0 + 16;
  if (r0 >= n_e) r0 = n_e - 1;
  if (r1 >= n_e) r1 = n_e - 1;
  const bf16_t* ga0 = h1 + (size_t)(off + r0) * ID + kbase + kch;
  const bf16_t* ga1 = h1 + (size_t)(off + r1) * ID + kbase + kch;
  const bf16_t* gb0 = W2T + ((size_t)e * HD + n_base + w * 16 + srow) * ID + kbase + kch;
  const int laofs0 = w * 1024 + lane * 8;
  const int laofs1 = laofs0 + 512;
  const int lbofs = w * 512 + lane * 8;

  f32x4 acc[2][4];
#pragma unroll
  for (int mt = 0; mt < 2; ++mt)
#pragma unroll
    for (int nt = 0; nt < 4; ++nt)
#pragma unroll
      for (int r = 0; r < 4; ++r) acc[mt][nt][r] = 0.f;

  GLOAD(ga0, &As[0][laofs0]);
  GLOAD(ga1, &As[0][laofs1]);
  GLOAD(gb0, &Bs[0][lbofs]);

#define NT2 (ID / 2 / 32)
  for (int kt = 0; kt < NT2; ++kt) {
    __syncthreads();
    const int cur = kt & 1;
    if (kt + 1 < NT2) {
      const int nxt = cur ^ 1;
      const size_t ko = (size_t)(kt + 1) * 32;
      GLOAD(ga0 + ko, &As[nxt][laofs0]);
      GLOAD(ga1 + ko, &As[nxt][laofs1]);
      GLOAD(gb0 + ko, &Bs[nxt][lbofs]);
    }
    bf16x8 af[2], bfr[4];
#pragma unroll
    for (int i = 0; i < 2; ++i)
      af[i] = *(const bf16x8*)(&As[cur][(w * 32 + i * 16 + lrow) * 32 + quad * 8]);
#pragma unroll
    for (int i = 0; i < 4; ++i)
      bfr[i] = *(const bf16x8*)(&Bs[cur][(i * 16 + lrow) * 32 + quad * 8]);
#pragma unroll
    for (int mt = 0; mt < 2; ++mt)
#pragma unroll
      for (int nt = 0; nt < 4; ++nt)
        acc[mt][nt] =
            __builtin_amdgcn_mfma_f32_16x16x32_bf16(af[mt], bfr[nt], acc[mt][nt], 0, 0, 0);
  }

#pragma unroll
  for (int mt = 0; mt < 2; ++mt) {
#pragma unroll
    for (int r = 0; r < 4; ++r) {
      const int gm = m_base + w * 32 + mt * 16 + quad * 4 + r;
      if (gm < n_e) {
        const int pos = off + gm;
        const int tokid = bucket_tok[pos];
        const float wgt = bucket_w[pos];
        float* orow = out + (size_t)tokid * HD;
#pragma unroll
        for (int nt = 0; nt < 4; ++nt) {
          const int gh = n_base + nt * 16 + lrow;
          float v = acc[mt][nt][r];
          if (split == 0) v += b2[e * HD + gh];  // bias once
          atomicAdd(orow + gh, wgt * v);
        }
      }
    }
  }
}

extern "C" void kernel_launch(void* const* d_in, const int* in_sizes, int n_in,
                              void* d_out, int out_size, void* d_ws, size_t ws_size,
                              hipStream_t stream) {
  const float* x = (const float*)d_in[0];
  const float* Wg = (const float*)d_in[1];
  const float* W1 = (const float*)d_in[2];
  const float* b1 = (const float*)d_in[3];
  const float* W2 = (const float*)d_in[4];
  const float* b2 = (const float*)d_in[5];
  float* out = (float*)d_out;
  char* ws = (char*)d_ws;

  int* counts = (int*)(ws + WS_COUNTS);
  int* offsets = (int*)(ws + WS_OFFSETS);
  int* cursor = (int*)(ws + WS_CURSOR);
  int* bucket_tok = (int*)(ws + WS_BTOK);
  float* bucket_w = (float*)(ws + WS_BW);
  int* tok_e = (int*)(ws + WS_TE);
  float* tok_w = (float*)(ws + WS_TW);
  int* wl_e = (int*)(ws + WS_WL);
  int* wl_m = wl_e + MAXWL;
  int* n_work = wl_m + MAXWL;
  bf16_t* xb = (bf16_t*)(ws + WS_XB);
  bf16_t* h1 = (bf16_t*)(ws + WS_H1);
  bf16_t* WT = (bf16_t*)(ws + WS_WT);

  zero_kernel<<<(TOKS * HD / 4) / 256, 256, 0, stream>>>(out, counts);
  gate_kernel<<<TOKS, 64, 0, stream>>>(x, Wg, xb, tok_e, tok_w, counts);
  scan_kernel<<<1, 64, 0, stream>>>(counts, offsets, cursor, wl_e, wl_m, n_work);
  scatter_kernel<<<TOKS * 2 / 256, 256, 0, stream>>>(tok_e, tok_w, cursor, bucket_tok, bucket_w);
  transpose_convert_kernel<<<dim3(HD / 64, ID / 64, NE), 256, 0, stream>>>(W1, WT, HD, ID);
  gemm1_kernel<<<dim3(MAXWL, ID / 64), 256, 0, stream>>>(xb, WT, b1, counts, offsets, bucket_tok,
                                                         wl_e, wl_m, n_work, h1);
  transpose_convert_kernel<<<dim3(ID / 64, HD / 64, NE), 256, 0, stream>>>(W2, WT, ID, HD);
  gemm2_kernel<<<dim3(MAXWL, HD / 64, 2), 256, 0, stream>>>(h1, WT, b2, counts, offsets,
                                                            bucket_tok, bucket_w, wl_e, wl_m,
                                                            n_work, out);
}